// Round 4
// baseline (80460.553 us; speedup 1.0000x reference)
//
#include <hip/hip_runtime.h>
#include <hip/hip_bf16.h>
#include <cstdint>
#include <cstddef>

#define T_DIM 512
#define B_DIM 256
#define D_DIM 256
#define H_DIM 512
#define O_DIM 256
#define NSTEP 10
#define WIN 16

__device__ __forceinline__ unsigned short f2bf(float f) {
    __hip_bfloat16 b = __float2bfloat16(f);   // RNE
    return *reinterpret_cast<unsigned short*>(&b);
}

// ---------------- transposes (tiny) ----------------
__global__ void k_transpose(const float* __restrict__ W_ih,
                            const float* __restrict__ W_out,
                            float* __restrict__ wihT,   // [256][512] d-major
                            float* __restrict__ woutT)  // [512][256] h-major
{
    int idx = blockIdx.x * blockDim.x + threadIdx.x;
    if (idx < 256 * 512) {
        int d = idx >> 9, h = idx & 511;
        wihT[d * 512 + h] = W_ih[h * 257 + d];   // W_ih row length = 257
    } else if (idx < 256 * 512 + 512 * 256) {
        int j = idx - 256 * 512;
        int h = j >> 8, o = j & 255;
        woutT[h * 256 + o] = W_out[o * 512 + h];
    }
}

// ---------------- sequential ACT recurrence, W_hh persistent in VGPRs ------
// 256 blocks x 1024 threads; block b owns batch row b; 1 block/CU.
// Thread (h = tid&511, kh = tid>>9) holds W_hh[h][kh*256 .. kh*256+256) in 64
// float4 registers, PINNED via empty asm so the compiler cannot rematerialize
// the global loads inside the ponder loop (round-3 failure: VGPR_Count=64,
// 91 GB of W re-fetch). __launch_bounds__(1024,4) raises the per-wave VGPR
// cap to 512 so 256 pinned + working set fit without spill.
__global__ __launch_bounds__(1024, 4) void k_recur4(
    const float* __restrict__ x,      // [T,B,256]
    const float* __restrict__ wihT,   // [256][512] d-major
    const float* __restrict__ W_hh,   // [512][512] row-major
    const float* __restrict__ W_ih,   // flag col at [h*257+256]
    const float* __restrict__ w_halt,
    const float* __restrict__ b_ih,
    const float* __restrict__ b_hh,
    const float* __restrict__ b_halt,
    float* out,                       // d_out (y region reused as bf16 s_acc)
    float* __restrict__ psum_g)       // [T*B]
{
    __shared__ __align__(16) float sb[2][H_DIM];     // s ping-pong
    __shared__ __align__(16) float xw[WIN][D_DIM];   // x window
    __shared__ __align__(16) float xcw[WIN][H_DIM];  // xc window
    __shared__ float part1[H_DIM];                   // kh=1 partial dots
    __shared__ float whalt_l[H_DIM];
    __shared__ float flag_l[H_DIM];
    __shared__ float bias_l[H_DIM];
    __shared__ float red[8];                         // wave sums (waves 0..7)

    const int tid = threadIdx.x;
    const int h = tid & 511;
    const int kh = tid >> 9;
    const int b = blockIdx.x;
    const int wave = tid >> 6;
    const int lane = tid & 63;

    if (!kh) {
        whalt_l[h] = w_halt[h];
        flag_l[h] = W_ih[h * 257 + 256];
        bias_l[h] = b_ih[h] + b_hh[h];
        sb[0][h] = 0.f;
    }

    // Persistent W slice: 64 float4 = 256 VGPRs, all statically indexed.
    float4 w4[64];
    {
        const float4* src = (const float4*)(W_hh + (size_t)h * H_DIM + kh * 256);
#pragma unroll
        for (int j = 0; j < 64; ++j) w4[j] = src[j];
    }
    // Pin: make values opaque so the compiler cannot sink/remat the loads
    // into the ponder loop. Values are unchanged (empty asm).
#pragma unroll
    for (int j = 0; j < 64; ++j) {
        asm volatile("" : "+v"(w4[j].x), "+v"(w4[j].y),
                          "+v"(w4[j].z), "+v"(w4[j].w));
    }
    __syncthreads();

    const float bh = b_halt[0];
    const float THR = 1.0f - 0.01f;
    unsigned short* sacc_out = (unsigned short*)out;  // bf16 staging in y region
    float* rho_out = out + (size_t)T_DIM * B_DIM * O_DIM;
    float* n_out = rho_out + (size_t)T_DIM * B_DIM;

    int cur = 0;
    for (int t = 0; t < T_DIM; ++t) {
        const int tw = t & (WIN - 1);
        if (tw == 0) {
            // stage x[t..t+WIN)[b][:]  (coalesced; 4 iters)
            for (int i = tid; i < WIN * D_DIM; i += 1024)
                xw[i >> 8][i & 255] =
                    x[((size_t)(t + (i >> 8)) * B_DIM + b) * D_DIM + (i & 255)];
            __syncthreads();
            // xcw[j][h] = sum_d xw[j][d] * wihT[d][h] + bias ; thread does
            // j = kh*8..kh*8+7. wihT coalesced across h; xw broadcast.
            float xa[8];
#pragma unroll
            for (int jj = 0; jj < 8; ++jj) xa[jj] = 0.f;
            for (int d = 0; d < 256; d += 4) {
                const float w0 = wihT[(d + 0) * 512 + h];
                const float w1 = wihT[(d + 1) * 512 + h];
                const float w2 = wihT[(d + 2) * 512 + h];
                const float w3 = wihT[(d + 3) * 512 + h];
#pragma unroll
                for (int jj = 0; jj < 8; ++jj) {
                    const float4 xv = *(const float4*)&xw[kh * 8 + jj][d];
                    xa[jj] += xv.x * w0;
                    xa[jj] += xv.y * w1;
                    xa[jj] += xv.z * w2;
                    xa[jj] += xv.w * w3;
                }
            }
#pragma unroll
            for (int jj = 0; jj < 8; ++jj)
                xcw[kh * 8 + jj][h] = xa[jj] + bias_l[h];
            __syncthreads();
        }

        float sacc_v = 0.f;
        float hsum = 0.f, runf = 1.f, stepsf = 0.f, remf = 0.f, psum_v = 0.f;

        for (int nstep = 0; nstep < NSTEP; ++nstep) {
            // ---- main dot: register W x LDS-broadcast s ----
            const float4* s4 = (const float4*)sb[cur] + kh * 64;
            float4 a0{0.f, 0.f, 0.f, 0.f}, a1 = a0, a2 = a0, a3 = a0;
#pragma unroll
            for (int j = 0; j < 16; ++j) {
                float4 sv, wv;
                sv = s4[j * 4 + 0]; wv = w4[j * 4 + 0];
                a0.x += sv.x * wv.x; a0.y += sv.y * wv.y;
                a0.z += sv.z * wv.z; a0.w += sv.w * wv.w;
                sv = s4[j * 4 + 1]; wv = w4[j * 4 + 1];
                a1.x += sv.x * wv.x; a1.y += sv.y * wv.y;
                a1.z += sv.z * wv.z; a1.w += sv.w * wv.w;
                sv = s4[j * 4 + 2]; wv = w4[j * 4 + 2];
                a2.x += sv.x * wv.x; a2.y += sv.y * wv.y;
                a2.z += sv.z * wv.z; a2.w += sv.w * wv.w;
                sv = s4[j * 4 + 3]; wv = w4[j * 4 + 3];
                a3.x += sv.x * wv.x; a3.y += sv.y * wv.y;
                a3.z += sv.z * wv.z; a3.w += sv.w * wv.w;
            }
            const float h0 = (a0.x + a0.y) + (a0.z + a0.w);
            const float h1 = (a1.x + a1.y) + (a1.z + a1.w);
            const float h2 = (a2.x + a2.y) + (a2.z + a2.w);
            const float h3 = (a3.x + a3.y) + (a3.z + a3.w);
            const float pd = (h0 + h1) + (h2 + h3);

            if (kh) part1[h] = pd;
            __syncthreads();   // A: part1 ready; sb[cur] fully consumed

            float sn = 0.f;
            if (!kh) {
                float base = xcw[tw][h];
                if (nstep == 0) base += flag_l[h];
                const float pre = (base + pd) + part1[h];
                sn = tanhf(pre);
                sb[cur ^ 1][h] = sn;
                float part = sn * whalt_l[h];
#pragma unroll
                for (int m = 1; m < 64; m <<= 1) part += __shfl_xor(part, m, 64);
                if (lane == 0) red[wave] = part;
            }
            __syncthreads();   // B: s-next + red ready

            // ---- halting scalars, replicated uniformly on all 1024 threads ----
            const float dotv = ((red[0] + red[1]) + (red[2] + red[3])) +
                               ((red[4] + red[5]) + (red[6] + red[7]));
            const float z = dotv + bh;
            const float hn = 1.f / (1.f + expf(-z));
            const float ns = hsum + hn;
            const float stop = (ns >= THR) ? runf : 0.f;
            const float still = runf - stop;
            const float rem = (1.f - hsum) * stop;
            const float p = hn * still + rem;
            if (!kh) sacc_v += p * sn;
            psum_v += p;
            stepsf += runf;   // old running, matches reference order
            remf += rem;
            hsum = ns;
            runf = still;
            cur ^= 1;
            if (still == 0.f) break;   // uniform across block
        }

        // epilogue: s(next t) = s_acc; bf16-stage s_acc; store psum/rho/n
        if (!kh) {
            sb[cur][h] = sacc_v;
            const size_t base = ((size_t)t * B_DIM + b) * (size_t)H_DIM + h;
            sacc_out[base] = f2bf(sacc_v);
        }
        if (tid == 0) {
            psum_g[t * B_DIM + b] = psum_v;
            rho_out[t * B_DIM + b] = stepsf + remf;
            n_out[t * B_DIM + b] = stepsf;
        }
        __syncthreads();   // C: protects sb[cur] overwrite + window reuse
    }
}

// ---------------- y = s_acc @ W_out.T + psum * b_out ----------------
// Reads bf16 s_acc from the y region of d_out, overwrites same rows with y.
__global__ __launch_bounds__(256) void k_y(
    const float* __restrict__ woutT,  // [512][256]
    const float* __restrict__ b_out,
    const float* __restrict__ psum_g,
    float* out)
{
    __shared__ float sl[16][512];
    __shared__ float pl[16];
    const int tid = threadIdx.x;
    const int tb0 = blockIdx.x * 16;
    const unsigned short* sacc = (const unsigned short*)out;
    for (int i = tid; i < 16 * 512; i += 256) {
        unsigned int u = sacc[(size_t)tb0 * 512 + i];
        u <<= 16;
        sl[i >> 9][i & 511] = __uint_as_float(u);
    }
    if (tid < 16) pl[tid] = psum_g[tb0 + tid];
    __syncthreads();
    const int o = tid;
    float acc[16];
#pragma unroll
    for (int r = 0; r < 16; ++r) acc[r] = 0.f;
    for (int hh = 0; hh < 512; hh += 4) {
        const float wv0 = woutT[(hh + 0) * 256 + o];
        const float wv1 = woutT[(hh + 1) * 256 + o];
        const float wv2 = woutT[(hh + 2) * 256 + o];
        const float wv3 = woutT[(hh + 3) * 256 + o];
#pragma unroll
        for (int r = 0; r < 16; ++r) {
            const float4 sv = *(const float4*)&sl[r][hh];
            acc[r] += sv.x * wv0;
            acc[r] += sv.y * wv1;
            acc[r] += sv.z * wv2;
            acc[r] += sv.w * wv3;
        }
    }
    const float bo = b_out[o];
    for (int r = 0; r < 16; ++r)
        out[(size_t)(tb0 + r) * 256 + o] = acc[r] + pl[r] * bo;
}

extern "C" void kernel_launch(void* const* d_in, const int* in_sizes, int n_in,
                              void* d_out, int out_size, void* d_ws, size_t ws_size,
                              hipStream_t stream) {
    const float* x = (const float*)d_in[0];
    const float* W_ih = (const float*)d_in[1];
    const float* b_ih = (const float*)d_in[2];
    const float* W_hh = (const float*)d_in[3];
    const float* b_hh = (const float*)d_in[4];
    const float* W_halt = (const float*)d_in[5];
    const float* b_halt = (const float*)d_in[6];
    const float* W_out = (const float*)d_in[7];
    const float* b_out = (const float*)d_in[8];
    float* out = (float*)d_out;

    char* ws = (char*)d_ws;
    float* wihT = (float*)ws;                        // 512 KB
    float* woutT = (float*)(ws + (512u << 10));      // 512 KB
    float* psum = (float*)(ws + (1u << 20));         // 512 KB

    hipLaunchKernelGGL(k_transpose, dim3(1024), dim3(256), 0, stream,
                       W_ih, W_out, wihT, woutT);
    hipLaunchKernelGGL(k_recur4, dim3(B_DIM), dim3(1024), 0, stream,
                       x, wihT, W_hh, W_ih, W_halt, b_ih, b_hh, b_halt,
                       out, psum);
    hipLaunchKernelGGL(k_y, dim3((T_DIM * B_DIM) / 16), dim3(256), 0, stream,
                       woutT, b_out, psum, out);
}

// Round 5
// 68247.693 us; speedup vs baseline: 1.1789x; 1.1789x over previous
//
#include <hip/hip_runtime.h>
#include <hip/hip_bf16.h>
#include <cstdint>
#include <cstddef>

#define T_DIM 512
#define B_DIM 256
#define D_DIM 256
#define H_DIM 512
#define O_DIM 256
#define NSTEP 10
#define WIN 16

__device__ __forceinline__ unsigned short f2bf(float f) {
    __hip_bfloat16 b = __float2bfloat16(f);   // RNE
    return *reinterpret_cast<unsigned short*>(&b);
}

// ---------------- transposes (tiny) ----------------
__global__ void k_transpose(const float* __restrict__ W_ih,
                            const float* __restrict__ W_out,
                            float* __restrict__ wihT,   // [256][512] d-major
                            float* __restrict__ woutT)  // [512][256] h-major
{
    int idx = blockIdx.x * blockDim.x + threadIdx.x;
    if (idx < 256 * 512) {
        int d = idx >> 9, h = idx & 511;
        wihT[d * 512 + h] = W_ih[h * 257 + d];   // W_ih row length = 257
    } else if (idx < 256 * 512 + 512 * 256) {
        int j = idx - 256 * 512;
        int h = j >> 8, o = j & 255;
        woutT[h * 256 + o] = W_out[o * 512 + h];
    }
}

// W slice: 64 INDIVIDUALLY NAMED float4 locals (no array -> no alloca -> no
// scratch demotion; round-4 failure mode). Each pinned opaque right after its
// load so the global load cannot be rematerialized inside the ponder loop.
#define WLOAD4(j0, j1, j2, j3)                                                \
    float4 w##j0 = wsrc[j0], w##j1 = wsrc[j1],                                \
           w##j2 = wsrc[j2], w##j3 = wsrc[j3];                                \
    asm volatile("" : "+v"(w##j0.x), "+v"(w##j0.y), "+v"(w##j0.z),            \
                      "+v"(w##j0.w), "+v"(w##j1.x), "+v"(w##j1.y),            \
                      "+v"(w##j1.z), "+v"(w##j1.w), "+v"(w##j2.x),            \
                      "+v"(w##j2.y), "+v"(w##j2.z), "+v"(w##j2.w),            \
                      "+v"(w##j3.x), "+v"(w##j3.y), "+v"(w##j3.z),            \
                      "+v"(w##j3.w));

// Same association as rounds 3/4: four float4 accumulator chains a0..a3,
// chain c takes s4[4i+c]*w(4i+c) elementwise, ascending i. fp contraction
// (v_fmac) identical -> bitwise-identical pre-activation.
#define WFMA4(j0, j1, j2, j3)                                                 \
    {                                                                         \
        float4 sv, wv;                                                        \
        sv = s4[j0]; wv = w##j0;                                              \
        a0.x += sv.x * wv.x; a0.y += sv.y * wv.y;                             \
        a0.z += sv.z * wv.z; a0.w += sv.w * wv.w;                             \
        sv = s4[j1]; wv = w##j1;                                              \
        a1.x += sv.x * wv.x; a1.y += sv.y * wv.y;                             \
        a1.z += sv.z * wv.z; a1.w += sv.w * wv.w;                             \
        sv = s4[j2]; wv = w##j2;                                              \
        a2.x += sv.x * wv.x; a2.y += sv.y * wv.y;                             \
        a2.z += sv.z * wv.z; a2.w += sv.w * wv.w;                             \
        sv = s4[j3]; wv = w##j3;                                              \
        a3.x += sv.x * wv.x; a3.y += sv.y * wv.y;                             \
        a3.z += sv.z * wv.z; a3.w += sv.w * wv.w;                             \
    }

// ---------------- sequential ACT recurrence, W_hh persistent in VGPRs ------
// 256 blocks x 1024 threads; block b owns batch row b; 1 block/CU.
// Thread (h = tid&511, kh = tid>>9) holds W_hh[h][kh*256 .. kh*256+256) in 64
// named float4 SSA values (256 VGPRs). __launch_bounds__(1024,4): 512-VGPR
// cap, demand ~340, per-SIMD 4 waves x 340 <= 2048-reg pool -> no spill.
__global__ __launch_bounds__(1024, 4) void k_recur5(
    const float* __restrict__ x,      // [T,B,256]
    const float* __restrict__ wihT,   // [256][512] d-major
    const float* __restrict__ W_hh,   // [512][512] row-major
    const float* __restrict__ W_ih,   // flag col at [h*257+256]
    const float* __restrict__ w_halt,
    const float* __restrict__ b_ih,
    const float* __restrict__ b_hh,
    const float* __restrict__ b_halt,
    float* out,                       // d_out (y region reused as bf16 s_acc)
    float* __restrict__ psum_g)       // [T*B]
{
    __shared__ __align__(16) float sb[2][H_DIM];     // s ping-pong
    __shared__ __align__(16) float xw[WIN][D_DIM];   // x window
    __shared__ __align__(16) float xcw[WIN][H_DIM];  // xc window
    __shared__ float part1[H_DIM];                   // kh=1 partial dots
    __shared__ float whalt_l[H_DIM];
    __shared__ float flag_l[H_DIM];
    __shared__ float bias_l[H_DIM];
    __shared__ float red[8];                         // wave sums (waves 0..7)

    const int tid = threadIdx.x;
    const int h = tid & 511;
    const int kh = tid >> 9;
    const int b = blockIdx.x;
    const int wave = tid >> 6;
    const int lane = tid & 63;

    if (!kh) {
        whalt_l[h] = w_halt[h];
        flag_l[h] = W_ih[h * 257 + 256];
        bias_l[h] = b_ih[h] + b_hh[h];
        sb[0][h] = 0.f;
    }

    const float4* wsrc = (const float4*)(W_hh + (size_t)h * H_DIM + kh * 256);
    WLOAD4(0, 1, 2, 3)     WLOAD4(4, 5, 6, 7)     WLOAD4(8, 9, 10, 11)
    WLOAD4(12, 13, 14, 15) WLOAD4(16, 17, 18, 19) WLOAD4(20, 21, 22, 23)
    WLOAD4(24, 25, 26, 27) WLOAD4(28, 29, 30, 31) WLOAD4(32, 33, 34, 35)
    WLOAD4(36, 37, 38, 39) WLOAD4(40, 41, 42, 43) WLOAD4(44, 45, 46, 47)
    WLOAD4(48, 49, 50, 51) WLOAD4(52, 53, 54, 55) WLOAD4(56, 57, 58, 59)
    WLOAD4(60, 61, 62, 63)
    __syncthreads();

    const float bh = b_halt[0];
    const float THR = 1.0f - 0.01f;
    unsigned short* sacc_out = (unsigned short*)out;  // bf16 staging in y region
    float* rho_out = out + (size_t)T_DIM * B_DIM * O_DIM;
    float* n_out = rho_out + (size_t)T_DIM * B_DIM;

    int cur = 0;
    for (int t = 0; t < T_DIM; ++t) {
        const int tw = t & (WIN - 1);
        if (tw == 0) {
            // stage x[t..t+WIN)[b][:]  (coalesced; 4 iters)
            for (int i = tid; i < WIN * D_DIM; i += 1024)
                xw[i >> 8][i & 255] =
                    x[((size_t)(t + (i >> 8)) * B_DIM + b) * D_DIM + (i & 255)];
            __syncthreads();
            // xcw[j][h] = sum_d xw[j][d] * wihT[d][h] + bias ; thread does
            // j = kh*8..kh*8+7. wihT coalesced across h; xw broadcast.
            float xa[8];
#pragma unroll
            for (int jj = 0; jj < 8; ++jj) xa[jj] = 0.f;
            for (int d = 0; d < 256; d += 4) {
                const float w0 = wihT[(d + 0) * 512 + h];
                const float w1 = wihT[(d + 1) * 512 + h];
                const float w2 = wihT[(d + 2) * 512 + h];
                const float w3 = wihT[(d + 3) * 512 + h];
#pragma unroll
                for (int jj = 0; jj < 8; ++jj) {
                    const float4 xv = *(const float4*)&xw[kh * 8 + jj][d];
                    xa[jj] += xv.x * w0;
                    xa[jj] += xv.y * w1;
                    xa[jj] += xv.z * w2;
                    xa[jj] += xv.w * w3;
                }
            }
#pragma unroll
            for (int jj = 0; jj < 8; ++jj)
                xcw[kh * 8 + jj][h] = xa[jj] + bias_l[h];
            __syncthreads();
        }

        float sacc_v = 0.f;
        float hsum = 0.f, runf = 1.f, stepsf = 0.f, remf = 0.f, psum_v = 0.f;

        for (int nstep = 0; nstep < NSTEP; ++nstep) {
            // ---- main dot: register W x LDS-broadcast s ----
            const float4* s4 = (const float4*)sb[cur] + kh * 64;
            float4 a0{0.f, 0.f, 0.f, 0.f}, a1 = a0, a2 = a0, a3 = a0;
            WFMA4(0, 1, 2, 3)     WFMA4(4, 5, 6, 7)     WFMA4(8, 9, 10, 11)
            WFMA4(12, 13, 14, 15) WFMA4(16, 17, 18, 19) WFMA4(20, 21, 22, 23)
            WFMA4(24, 25, 26, 27) WFMA4(28, 29, 30, 31) WFMA4(32, 33, 34, 35)
            WFMA4(36, 37, 38, 39) WFMA4(40, 41, 42, 43) WFMA4(44, 45, 46, 47)
            WFMA4(48, 49, 50, 51) WFMA4(52, 53, 54, 55) WFMA4(56, 57, 58, 59)
            WFMA4(60, 61, 62, 63)
            const float h0 = (a0.x + a0.y) + (a0.z + a0.w);
            const float h1 = (a1.x + a1.y) + (a1.z + a1.w);
            const float h2 = (a2.x + a2.y) + (a2.z + a2.w);
            const float h3 = (a3.x + a3.y) + (a3.z + a3.w);
            const float pd = (h0 + h1) + (h2 + h3);

            if (kh) part1[h] = pd;
            __syncthreads();   // A: part1 ready; sb[cur] fully consumed

            float sn = 0.f;
            if (!kh) {
                float base = xcw[tw][h];
                if (nstep == 0) base += flag_l[h];
                const float pre = (base + pd) + part1[h];
                sn = tanhf(pre);
                sb[cur ^ 1][h] = sn;
                float part = sn * whalt_l[h];
#pragma unroll
                for (int m = 1; m < 64; m <<= 1) part += __shfl_xor(part, m, 64);
                if (lane == 0) red[wave] = part;
            }
            __syncthreads();   // B: s-next + red ready

            // ---- halting scalars, replicated uniformly on all 1024 threads ----
            const float dotv = ((red[0] + red[1]) + (red[2] + red[3])) +
                               ((red[4] + red[5]) + (red[6] + red[7]));
            const float z = dotv + bh;
            const float hn = 1.f / (1.f + expf(-z));
            const float ns = hsum + hn;
            const float stop = (ns >= THR) ? runf : 0.f;
            const float still = runf - stop;
            const float rem = (1.f - hsum) * stop;
            const float p = hn * still + rem;
            if (!kh) sacc_v += p * sn;
            psum_v += p;
            stepsf += runf;   // old running, matches reference order
            remf += rem;
            hsum = ns;
            runf = still;
            cur ^= 1;
            if (still == 0.f) break;   // uniform across block
        }

        // epilogue: s(next t) = s_acc; bf16-stage s_acc; store psum/rho/n
        if (!kh) {
            sb[cur][h] = sacc_v;
            const size_t base = ((size_t)t * B_DIM + b) * (size_t)H_DIM + h;
            sacc_out[base] = f2bf(sacc_v);
        }
        if (tid == 0) {
            psum_g[t * B_DIM + b] = psum_v;
            rho_out[t * B_DIM + b] = stepsf + remf;
            n_out[t * B_DIM + b] = stepsf;
        }
        __syncthreads();   // C: protects sb[cur] overwrite + window reuse
    }
}

// ---------------- y = s_acc @ W_out.T + psum * b_out ----------------
// Reads bf16 s_acc from the y region of d_out, overwrites same rows with y.
__global__ __launch_bounds__(256) void k_y(
    const float* __restrict__ woutT,  // [512][256]
    const float* __restrict__ b_out,
    const float* __restrict__ psum_g,
    float* out)
{
    __shared__ float sl[16][512];
    __shared__ float pl[16];
    const int tid = threadIdx.x;
    const int tb0 = blockIdx.x * 16;
    const unsigned short* sacc = (const unsigned short*)out;
    for (int i = tid; i < 16 * 512; i += 256) {
        unsigned int u = sacc[(size_t)tb0 * 512 + i];
        u <<= 16;
        sl[i >> 9][i & 511] = __uint_as_float(u);
    }
    if (tid < 16) pl[tid] = psum_g[tb0 + tid];
    __syncthreads();
    const int o = tid;
    float acc[16];
#pragma unroll
    for (int r = 0; r < 16; ++r) acc[r] = 0.f;
    for (int hh = 0; hh < 512; hh += 4) {
        const float wv0 = woutT[(hh + 0) * 256 + o];
        const float wv1 = woutT[(hh + 1) * 256 + o];
        const float wv2 = woutT[(hh + 2) * 256 + o];
        const float wv3 = woutT[(hh + 3) * 256 + o];
#pragma unroll
        for (int r = 0; r < 16; ++r) {
            const float4 sv = *(const float4*)&sl[r][hh];
            acc[r] += sv.x * wv0;
            acc[r] += sv.y * wv1;
            acc[r] += sv.z * wv2;
            acc[r] += sv.w * wv3;
        }
    }
    const float bo = b_out[o];
    for (int r = 0; r < 16; ++r)
        out[(size_t)(tb0 + r) * 256 + o] = acc[r] + pl[r] * bo;
}

extern "C" void kernel_launch(void* const* d_in, const int* in_sizes, int n_in,
                              void* d_out, int out_size, void* d_ws, size_t ws_size,
                              hipStream_t stream) {
    const float* x = (const float*)d_in[0];
    const float* W_ih = (const float*)d_in[1];
    const float* b_ih = (const float*)d_in[2];
    const float* W_hh = (const float*)d_in[3];
    const float* b_hh = (const float*)d_in[4];
    const float* W_halt = (const float*)d_in[5];
    const float* b_halt = (const float*)d_in[6];
    const float* W_out = (const float*)d_in[7];
    const float* b_out = (const float*)d_in[8];
    float* out = (float*)d_out;

    char* ws = (char*)d_ws;
    float* wihT = (float*)ws;                        // 512 KB
    float* woutT = (float*)(ws + (512u << 10));      // 512 KB
    float* psum = (float*)(ws + (1u << 20));         // 512 KB

    hipLaunchKernelGGL(k_transpose, dim3(1024), dim3(256), 0, stream,
                       W_ih, W_out, wihT, woutT);
    hipLaunchKernelGGL(k_recur5, dim3(B_DIM), dim3(1024), 0, stream,
                       x, wihT, W_hh, W_ih, W_halt, b_ih, b_hh, b_halt,
                       out, psum);
    hipLaunchKernelGGL(k_y, dim3((T_DIM * B_DIM) / 16), dim3(256), 0, stream,
                       woutT, b_out, psum, out);
}

// Round 6
// 62394.171 us; speedup vs baseline: 1.2896x; 1.0938x over previous
//
#include <hip/hip_runtime.h>
#include <hip/hip_bf16.h>
#include <cstdint>
#include <cstddef>

#define T_DIM 512
#define B_DIM 256
#define D_DIM 256
#define H_DIM 512
#define O_DIM 256
#define NSTEP 10
#define WIN 16

__device__ __forceinline__ unsigned short f2bf(float f) {
    __hip_bfloat16 b = __float2bfloat16(f);   // RNE
    return *reinterpret_cast<unsigned short*>(&b);
}

// ---------------- transposes (tiny) ----------------
__global__ void k_transpose(const float* __restrict__ W_ih,
                            const float* __restrict__ W_out,
                            float* __restrict__ wihT,   // [256][512] d-major
                            float* __restrict__ woutT)  // [512][256] h-major
{
    int idx = blockIdx.x * blockDim.x + threadIdx.x;
    if (idx < 256 * 512) {
        int d = idx >> 9, h = idx & 511;
        wihT[d * 512 + h] = W_ih[h * 257 + d];   // W_ih row length = 257
    } else if (idx < 256 * 512 + 512 * 256) {
        int j = idx - 256 * 512;
        int h = j >> 8, o = j & 255;
        woutT[h * 256 + o] = W_out[o * 512 + h];
    }
}

// ---- W slice pinned in AGPRs ------------------------------------------------
// Rounds 3-5 proved hipcc will not keep these 256 floats in arch VGPRs (it
// rematerializes the global loads inside the ponder loop: VGPR_Count=64,
// 90-175 GB FETCH). So we place them in the AGPR file explicitly: the "a"
// constraint forces AGPR allocation; the producer is volatile asm so remat
// from W_hh is illegal; AGPRs have zero competing pressure in this kernel.
#define WLOADA(j)                                                              \
    float wa##j##x, wa##j##y, wa##j##z, wa##j##w;                              \
    {                                                                          \
        const float4 twj = wsrc[j];                                           \
        asm volatile("v_accvgpr_write_b32 %0, %1"                              \
                     : "=a"(wa##j##x) : "v"(twj.x));                           \
        asm volatile("v_accvgpr_write_b32 %0, %1"                              \
                     : "=a"(wa##j##y) : "v"(twj.y));                           \
        asm volatile("v_accvgpr_write_b32 %0, %1"                              \
                     : "=a"(wa##j##z) : "v"(twj.z));                           \
        asm volatile("v_accvgpr_write_b32 %0, %1"                              \
                     : "=a"(wa##j##w) : "v"(twj.w));                           \
    }

// Same token-level association as rounds 3-5: chain a0 consumes s4[4i+0],
// a1 s4[4i+1], a2 s4[4i+2], a3 s4[4i+3], ascending i, elementwise x,y,z,w.
// v_fmac contraction identical -> bitwise-identical pre-activation.
#define WFMA_G(j, acc)                                                         \
    {                                                                          \
        const float4 sv = s4[j];                                               \
        float wx, wy, wz, ww;                                                  \
        asm volatile("v_accvgpr_read_b32 %0, %1" : "=v"(wx) : "a"(wa##j##x));  \
        asm volatile("v_accvgpr_read_b32 %0, %1" : "=v"(wy) : "a"(wa##j##y));  \
        asm volatile("v_accvgpr_read_b32 %0, %1" : "=v"(wz) : "a"(wa##j##z));  \
        asm volatile("v_accvgpr_read_b32 %0, %1" : "=v"(ww) : "a"(wa##j##w));  \
        acc.x += sv.x * wx; acc.y += sv.y * wy;                                \
        acc.z += sv.z * wz; acc.w += sv.w * ww;                                \
    }
#define WFMA4(j0, j1, j2, j3)                                                  \
    WFMA_G(j0, a0) WFMA_G(j1, a1) WFMA_G(j2, a2) WFMA_G(j3, a3)

// ---------------- sequential ACT recurrence, W_hh persistent in AGPRs ------
// 256 blocks x 1024 threads; block b owns batch row b; 1 block/CU.
// Thread (h = tid&511, kh = tid>>9) holds W_hh[h][kh*256 .. kh*256+256) in
// 256 AGPRs. __launch_bounds__(1024,1): 512-reg budget under either reading
// of the 2nd arg (1 wave/EU -> 512; or 1 wg/CU = 4 waves/SIMD -> 512).
__global__ __launch_bounds__(1024, 1) void k_recur6(
    const float* __restrict__ x,      // [T,B,256]
    const float* __restrict__ wihT,   // [256][512] d-major
    const float* __restrict__ W_hh,   // [512][512] row-major
    const float* __restrict__ W_ih,   // flag col at [h*257+256]
    const float* __restrict__ w_halt,
    const float* __restrict__ b_ih,
    const float* __restrict__ b_hh,
    const float* __restrict__ b_halt,
    float* out,                       // d_out (y region reused as bf16 s_acc)
    float* __restrict__ psum_g)       // [T*B]
{
    __shared__ __align__(16) float sb[2][H_DIM];     // s ping-pong
    __shared__ __align__(16) float xw[WIN][D_DIM];   // x window
    __shared__ __align__(16) float xcw[WIN][H_DIM];  // xc window
    __shared__ float part1[H_DIM];                   // kh=1 partial dots
    __shared__ float whalt_l[H_DIM];
    __shared__ float flag_l[H_DIM];
    __shared__ float bias_l[H_DIM];
    __shared__ float red[8];                         // wave sums (waves 0..7)

    const int tid = threadIdx.x;
    const int h = tid & 511;
    const int kh = tid >> 9;
    const int b = blockIdx.x;
    const int wave = tid >> 6;
    const int lane = tid & 63;

    if (!kh) {
        whalt_l[h] = w_halt[h];
        flag_l[h] = W_ih[h * 257 + 256];
        bias_l[h] = b_ih[h] + b_hh[h];
        sb[0][h] = 0.f;
    }

    const float4* wsrc = (const float4*)(W_hh + (size_t)h * H_DIM + kh * 256);
    WLOADA(0)  WLOADA(1)  WLOADA(2)  WLOADA(3)  WLOADA(4)  WLOADA(5)
    WLOADA(6)  WLOADA(7)  WLOADA(8)  WLOADA(9)  WLOADA(10) WLOADA(11)
    WLOADA(12) WLOADA(13) WLOADA(14) WLOADA(15) WLOADA(16) WLOADA(17)
    WLOADA(18) WLOADA(19) WLOADA(20) WLOADA(21) WLOADA(22) WLOADA(23)
    WLOADA(24) WLOADA(25) WLOADA(26) WLOADA(27) WLOADA(28) WLOADA(29)
    WLOADA(30) WLOADA(31) WLOADA(32) WLOADA(33) WLOADA(34) WLOADA(35)
    WLOADA(36) WLOADA(37) WLOADA(38) WLOADA(39) WLOADA(40) WLOADA(41)
    WLOADA(42) WLOADA(43) WLOADA(44) WLOADA(45) WLOADA(46) WLOADA(47)
    WLOADA(48) WLOADA(49) WLOADA(50) WLOADA(51) WLOADA(52) WLOADA(53)
    WLOADA(54) WLOADA(55) WLOADA(56) WLOADA(57) WLOADA(58) WLOADA(59)
    WLOADA(60) WLOADA(61) WLOADA(62) WLOADA(63)
    __syncthreads();

    const float bh = b_halt[0];
    const float THR = 1.0f - 0.01f;
    unsigned short* sacc_out = (unsigned short*)out;  // bf16 staging in y region
    float* rho_out = out + (size_t)T_DIM * B_DIM * O_DIM;
    float* n_out = rho_out + (size_t)T_DIM * B_DIM;

    int cur = 0;
    for (int t = 0; t < T_DIM; ++t) {
        const int tw = t & (WIN - 1);
        if (tw == 0) {
            // stage x[t..t+WIN)[b][:]  (coalesced; 4 iters)
            for (int i = tid; i < WIN * D_DIM; i += 1024)
                xw[i >> 8][i & 255] =
                    x[((size_t)(t + (i >> 8)) * B_DIM + b) * D_DIM + (i & 255)];
            __syncthreads();
            // xcw[j][h] = sum_d xw[j][d] * wihT[d][h] + bias ; thread does
            // j = kh*8..kh*8+7. wihT coalesced across h; xw broadcast.
            float xa[8];
#pragma unroll
            for (int jj = 0; jj < 8; ++jj) xa[jj] = 0.f;
            for (int d = 0; d < 256; d += 4) {
                const float w0 = wihT[(d + 0) * 512 + h];
                const float w1 = wihT[(d + 1) * 512 + h];
                const float w2 = wihT[(d + 2) * 512 + h];
                const float w3 = wihT[(d + 3) * 512 + h];
#pragma unroll
                for (int jj = 0; jj < 8; ++jj) {
                    const float4 xv = *(const float4*)&xw[kh * 8 + jj][d];
                    xa[jj] += xv.x * w0;
                    xa[jj] += xv.y * w1;
                    xa[jj] += xv.z * w2;
                    xa[jj] += xv.w * w3;
                }
            }
#pragma unroll
            for (int jj = 0; jj < 8; ++jj)
                xcw[kh * 8 + jj][h] = xa[jj] + bias_l[h];
            __syncthreads();
        }

        float sacc_v = 0.f;
        float hsum = 0.f, runf = 1.f, stepsf = 0.f, remf = 0.f, psum_v = 0.f;

        for (int nstep = 0; nstep < NSTEP; ++nstep) {
            // ---- main dot: AGPR-resident W x LDS-broadcast s ----
            const float4* s4 = (const float4*)sb[cur] + kh * 64;
            float4 a0{0.f, 0.f, 0.f, 0.f}, a1 = a0, a2 = a0, a3 = a0;
            WFMA4(0, 1, 2, 3)     WFMA4(4, 5, 6, 7)     WFMA4(8, 9, 10, 11)
            WFMA4(12, 13, 14, 15) WFMA4(16, 17, 18, 19) WFMA4(20, 21, 22, 23)
            WFMA4(24, 25, 26, 27) WFMA4(28, 29, 30, 31) WFMA4(32, 33, 34, 35)
            WFMA4(36, 37, 38, 39) WFMA4(40, 41, 42, 43) WFMA4(44, 45, 46, 47)
            WFMA4(48, 49, 50, 51) WFMA4(52, 53, 54, 55) WFMA4(56, 57, 58, 59)
            WFMA4(60, 61, 62, 63)
            const float h0 = (a0.x + a0.y) + (a0.z + a0.w);
            const float h1 = (a1.x + a1.y) + (a1.z + a1.w);
            const float h2 = (a2.x + a2.y) + (a2.z + a2.w);
            const float h3 = (a3.x + a3.y) + (a3.z + a3.w);
            const float pd = (h0 + h1) + (h2 + h3);

            if (kh) part1[h] = pd;
            __syncthreads();   // A: part1 ready; sb[cur] fully consumed

            float sn = 0.f;
            if (!kh) {
                float base = xcw[tw][h];
                if (nstep == 0) base += flag_l[h];
                const float pre = (base + pd) + part1[h];
                sn = tanhf(pre);
                sb[cur ^ 1][h] = sn;
                float part = sn * whalt_l[h];
#pragma unroll
                for (int m = 1; m < 64; m <<= 1) part += __shfl_xor(part, m, 64);
                if (lane == 0) red[wave] = part;
            }
            __syncthreads();   // B: s-next + red ready

            // ---- halting scalars, replicated uniformly on all 1024 threads ----
            const float dotv = ((red[0] + red[1]) + (red[2] + red[3])) +
                               ((red[4] + red[5]) + (red[6] + red[7]));
            const float z = dotv + bh;
            const float hn = 1.f / (1.f + expf(-z));
            const float ns = hsum + hn;
            const float stop = (ns >= THR) ? runf : 0.f;
            const float still = runf - stop;
            const float rem = (1.f - hsum) * stop;
            const float p = hn * still + rem;
            if (!kh) sacc_v += p * sn;
            psum_v += p;
            stepsf += runf;   // old running, matches reference order
            remf += rem;
            hsum = ns;
            runf = still;
            cur ^= 1;
            if (still == 0.f) break;   // uniform across block
        }

        // epilogue: s(next t) = s_acc; bf16-stage s_acc; store psum/rho/n
        if (!kh) {
            sb[cur][h] = sacc_v;
            const size_t base = ((size_t)t * B_DIM + b) * (size_t)H_DIM + h;
            sacc_out[base] = f2bf(sacc_v);
        }
        if (tid == 0) {
            psum_g[t * B_DIM + b] = psum_v;
            rho_out[t * B_DIM + b] = stepsf + remf;
            n_out[t * B_DIM + b] = stepsf;
        }
        __syncthreads();   // C: protects sb[cur] overwrite + window reuse
    }
}

// ---------------- y = s_acc @ W_out.T + psum * b_out ----------------
// Reads bf16 s_acc from the y region of d_out, overwrites same rows with y.
__global__ __launch_bounds__(256) void k_y(
    const float* __restrict__ woutT,  // [512][256]
    const float* __restrict__ b_out,
    const float* __restrict__ psum_g,
    float* out)
{
    __shared__ float sl[16][512];
    __shared__ float pl[16];
    const int tid = threadIdx.x;
    const int tb0 = blockIdx.x * 16;
    const unsigned short* sacc = (const unsigned short*)out;
    for (int i = tid; i < 16 * 512; i += 256) {
        unsigned int u = sacc[(size_t)tb0 * 512 + i];
        u <<= 16;
        sl[i >> 9][i & 511] = __uint_as_float(u);
    }
    if (tid < 16) pl[tid] = psum_g[tb0 + tid];
    __syncthreads();
    const int o = tid;
    float acc[16];
#pragma unroll
    for (int r = 0; r < 16; ++r) acc[r] = 0.f;
    for (int hh = 0; hh < 512; hh += 4) {
        const float wv0 = woutT[(hh + 0) * 256 + o];
        const float wv1 = woutT[(hh + 1) * 256 + o];
        const float wv2 = woutT[(hh + 2) * 256 + o];
        const float wv3 = woutT[(hh + 3) * 256 + o];
#pragma unroll
        for (int r = 0; r < 16; ++r) {
            const float4 sv = *(const float4*)&sl[r][hh];
            acc[r] += sv.x * wv0;
            acc[r] += sv.y * wv1;
            acc[r] += sv.z * wv2;
            acc[r] += sv.w * wv3;
        }
    }
    const float bo = b_out[o];
    for (int r = 0; r < 16; ++r)
        out[(size_t)(tb0 + r) * 256 + o] = acc[r] + pl[r] * bo;
}

extern "C" void kernel_launch(void* const* d_in, const int* in_sizes, int n_in,
                              void* d_out, int out_size, void* d_ws, size_t ws_size,
                              hipStream_t stream) {
    const float* x = (const float*)d_in[0];
    const float* W_ih = (const float*)d_in[1];
    const float* b_ih = (const float*)d_in[2];
    const float* W_hh = (const float*)d_in[3];
    const float* b_hh = (const float*)d_in[4];
    const float* W_halt = (const float*)d_in[5];
    const float* b_halt = (const float*)d_in[6];
    const float* W_out = (const float*)d_in[7];
    const float* b_out = (const float*)d_in[8];
    float* out = (float*)d_out;

    char* ws = (char*)d_ws;
    float* wihT = (float*)ws;                        // 512 KB
    float* woutT = (float*)(ws + (512u << 10));      // 512 KB
    float* psum = (float*)(ws + (1u << 20));         // 512 KB

    hipLaunchKernelGGL(k_transpose, dim3(1024), dim3(256), 0, stream,
                       W_ih, W_out, wihT, woutT);
    hipLaunchKernelGGL(k_recur6, dim3(B_DIM), dim3(1024), 0, stream,
                       x, wihT, W_hh, W_ih, W_halt, b_ih, b_hh, b_halt,
                       out, psum);
    hipLaunchKernelGGL(k_y, dim3((T_DIM * B_DIM) / 16), dim3(256), 0, stream,
                       woutT, b_out, psum, out);
}

// Round 7
// 14899.959 us; speedup vs baseline: 5.4001x; 4.1875x over previous
//
#include <hip/hip_runtime.h>
#include <hip/hip_bf16.h>
#include <cstdint>
#include <cstddef>

#define T_DIM 512
#define B_DIM 256
#define D_DIM 256
#define H_DIM 512
#define O_DIM 256
#define NSTEP 10
#define WIN 16

__device__ __forceinline__ unsigned short f2bf(float f) {
    __hip_bfloat16 b = __float2bfloat16(f);   // RNE
    return *reinterpret_cast<unsigned short*>(&b);
}

// ---------------- transposes (tiny) ----------------
__global__ void k_transpose(const float* __restrict__ W_hh,
                            const float* __restrict__ W_ih,
                            const float* __restrict__ W_out,
                            float* __restrict__ whhT,   // [512][512] k-major
                            float* __restrict__ wihT,   // [256][512] d-major
                            float* __restrict__ woutT)  // [512][256] h-major
{
    int idx = blockIdx.x * blockDim.x + threadIdx.x;
    if (idx < 512 * 512) {
        int k = idx >> 9, h = idx & 511;
        whhT[k * 512 + h] = W_hh[h * 512 + k];
    } else if (idx < 512 * 512 + 256 * 512) {
        int j = idx - 512 * 512;
        int d = j >> 9, h = j & 511;
        wihT[d * 512 + h] = W_ih[h * 257 + d];   // W_ih row length = 257
    } else if (idx < 512 * 512 + 256 * 512 + 512 * 256) {
        int j = idx - (512 * 512 + 256 * 512);
        int h = j >> 8, o = j & 255;
        woutT[h * 256 + o] = W_out[o * 512 + h];
    }
}

// ---------------- sequential ACT recurrence: coalesced W stream ----------
// 128 blocks x 1024 threads; block owns batch rows b0=2*blk, b0+1.
// Thread (h = tid&511, kh = tid>>9) accumulates k-half kh of column h for
// BOTH rows. W streamed k-major (whhT) -> lane h reads whhT[k*512+h]:
// fully coalesced, no register buffer (r1 spill trap), no LDS staging, no
// barriers inside the stream. Rows run at INDEPENDENT (t, nstep): every
// W-pass advances both rows' current ponder step (no lockstep max penalty).
// Row r's per-h post-processing is done by the kh==r half (all threads busy);
// halting scalars replicated uniformly on all 1024 threads.
// All summation trees token-identical to round 3 -> bitwise-same outputs.
__global__ __launch_bounds__(1024, 1) void k_recur7(
    const float* __restrict__ x,      // [T,B,256]
    const float* __restrict__ wihT,   // [256][512] d-major
    const float* __restrict__ whhT,   // [512][512] k-major
    const float* __restrict__ W_ih,   // flag col at [h*257+256]
    const float* __restrict__ w_halt,
    const float* __restrict__ b_ih,
    const float* __restrict__ b_hh,
    const float* __restrict__ b_halt,
    float* out,                       // d_out (y region reused as bf16 s_acc)
    float* __restrict__ psum_g)       // [T*B]
{
    __shared__ __align__(16) float sb[2][2][H_DIM];    // [row][pingpong][k] 8K
    __shared__ __align__(16) float xcw[2][WIN][H_DIM]; // [row][tw][h]     64K
    __shared__ float prt[2][2][H_DIM];                 // [kh][row][h]      8K
    __shared__ __align__(16) float xst[WIN * D_DIM];   // x staging        16K
    __shared__ float whalt_l[H_DIM];
    __shared__ float flag_l[H_DIM];
    __shared__ float bias_l[H_DIM];
    __shared__ float red[16];                          // wave sums

    const int tid = threadIdx.x;
    const int h = tid & 511;
    const int kh = tid >> 9;
    const int b0 = blockIdx.x * 2;
    const int wave = tid >> 6;       // 0..15 (row0: 0..7, row1: 8..15)
    const int lane = tid & 63;

    if (!kh) {
        whalt_l[h] = w_halt[h];
        flag_l[h] = W_ih[h * 257 + 256];
        bias_l[h] = b_ih[h] + b_hh[h];
    }
    sb[kh][0][h] = 0.f;   // s init for row kh (thread h of half kh)

    const float bh = b_halt[0];
    const float THR = 1.0f - 0.01f;
    unsigned short* sacc_out = (unsigned short*)out;  // bf16 staging (y region)
    float* rho_out = out + (size_t)T_DIM * B_DIM * O_DIM;
    float* n_out = rho_out + (size_t)T_DIM * B_DIM;

    // W column pointer for this thread's (h, k-half): element k_local at
    // wc[k_local*512] == W_hh[h][kh*256 + k_local].
    const float* wc = whhT + (size_t)kh * 256 * 512 + h;

    // ---- per-row replicated state (all threads) ----
    int t0 = 0, t1 = 0, nst0 = 0, nst1 = 0, cur0 = 0, cur1 = 0;
    int act0 = 1, act1 = 1;
    float hsum0 = 0.f, runf0 = 1.f, steps0 = 0.f, rem0 = 0.f, ps0 = 0.f;
    float hsum1 = 0.f, runf1 = 1.f, steps1 = 0.f, rem1 = 0.f, ps1 = 0.f;
    float sacc_v = 0.f;   // processor-only (row kh)
    int refill0 = 1, refill1 = 1;   // initial windows at t=0

    // refill macro: stage x[tb..tb+WIN)[br][:], then windowed xc GEMM.
    // Identical single-ascending-d fma chain as rounds 0-6 (bitwise).
#define DO_REFILL(RROW, TB, BR)                                               \
    {                                                                         \
        __syncthreads();                                                      \
        for (int i = tid; i < WIN * D_DIM; i += 1024)                         \
            xst[i] = x[((size_t)((TB) + (i >> 8)) * B_DIM + (BR)) * D_DIM +   \
                       (i & 255)];                                            \
        __syncthreads();                                                      \
        float xa[8];                                                          \
        _Pragma("unroll") for (int jj = 0; jj < 8; ++jj) xa[jj] = 0.f;        \
        for (int d = 0; d < 256; d += 4) {                                    \
            const float u0 = wihT[(d + 0) * 512 + h];                         \
            const float u1 = wihT[(d + 1) * 512 + h];                         \
            const float u2 = wihT[(d + 2) * 512 + h];                         \
            const float u3 = wihT[(d + 3) * 512 + h];                         \
            _Pragma("unroll") for (int jj = 0; jj < 8; ++jj) {                \
                const float4 xv =                                             \
                    *(const float4*)&xst[(kh * 8 + jj) * 256 + d];            \
                xa[jj] += xv.x * u0;                                          \
                xa[jj] += xv.y * u1;                                          \
                xa[jj] += xv.z * u2;                                          \
                xa[jj] += xv.w * u3;                                          \
            }                                                                 \
        }                                                                     \
        _Pragma("unroll") for (int jj = 0; jj < 8; ++jj)                      \
            xcw[RROW][kh * 8 + jj][h] = xa[jj] + bias_l[h];                   \
        __syncthreads();                                                      \
    }

    DO_REFILL(0, 0, b0)
    DO_REFILL(1, 0, b0 + 1)

    while (act0 || act1) {
        // ---- phase 1: barrier-free coalesced W stream, both rows ----
        // Association == r3: chain A_c consumes k in [16i+4c, 16i+4c+4).
        const float* s0p = &sb[0][cur0][kh << 8];
        const float* s1p = &sb[1][cur1][kh << 8];
        float4 A0[4], A1[4];
#pragma unroll
        for (int c = 0; c < 4; ++c) {
            A0[c] = float4{0.f, 0.f, 0.f, 0.f};
            A1[c] = float4{0.f, 0.f, 0.f, 0.f};
        }
#pragma unroll 4
        for (int i = 0; i < 16; ++i) {
#pragma unroll
            for (int c = 0; c < 4; ++c) {
                const int kbase = i * 16 + c * 4;
                const float4 sv0 = *(const float4*)&s0p[kbase];
                const float4 sv1 = *(const float4*)&s1p[kbase];
                const float w0 = wc[(size_t)(kbase + 0) * 512];
                const float w1 = wc[(size_t)(kbase + 1) * 512];
                const float w2 = wc[(size_t)(kbase + 2) * 512];
                const float w3 = wc[(size_t)(kbase + 3) * 512];
                A0[c].x += sv0.x * w0; A0[c].y += sv0.y * w1;
                A0[c].z += sv0.z * w2; A0[c].w += sv0.w * w3;
                A1[c].x += sv1.x * w0; A1[c].y += sv1.y * w1;
                A1[c].z += sv1.z * w2; A1[c].w += sv1.w * w3;
            }
        }
        {
            const float g0 = (A0[0].x + A0[0].y) + (A0[0].z + A0[0].w);
            const float g1 = (A0[1].x + A0[1].y) + (A0[1].z + A0[1].w);
            const float g2 = (A0[2].x + A0[2].y) + (A0[2].z + A0[2].w);
            const float g3 = (A0[3].x + A0[3].y) + (A0[3].z + A0[3].w);
            prt[kh][0][h] = (g0 + g1) + (g2 + g3);
        }
        {
            const float g0 = (A1[0].x + A1[0].y) + (A1[0].z + A1[0].w);
            const float g1 = (A1[1].x + A1[1].y) + (A1[1].z + A1[1].w);
            const float g2 = (A1[2].x + A1[2].y) + (A1[2].z + A1[2].w);
            const float g3 = (A1[3].x + A1[3].y) + (A1[3].z + A1[3].w);
            prt[kh][1][h] = (g0 + g1) + (g2 + g3);
        }
        __syncthreads();   // A: partials ready; sb fully consumed

        // ---- phase 2: row kh post-processing by this half ----
        const int myact = kh ? act1 : act0;
        const int mynst = kh ? nst1 : nst0;
        const int mytw = (kh ? t1 : t0) & (WIN - 1);
        float sn = 0.f;
        if (myact) {
            float base = xcw[kh][mytw][h];
            if (mynst == 0) base += flag_l[h];
            const float pre = (base + prt[0][kh][h]) + prt[1][kh][h];
            sn = tanhf(pre);
            sb[kh][(kh ? cur1 : cur0) ^ 1][h] = sn;
            float pt = sn * whalt_l[h];
#pragma unroll
            for (int m = 1; m < 64; m <<= 1) pt += __shfl_xor(pt, m, 64);
            if (lane == 0) red[wave] = pt;
        }
        __syncthreads();   // B: s-next + red ready

        // ---- phase 3: halting scalars, replicated on all threads ----
        int adv0 = 0, adv1 = 0;
        float p_mine = 0.f;
        if (act0) {
            const float dotv = ((red[0] + red[1]) + (red[2] + red[3])) +
                               ((red[4] + red[5]) + (red[6] + red[7]));
            const float z = dotv + bh;
            const float hn = 1.f / (1.f + expf(-z));
            const float ns = hsum0 + hn;
            const float stop = (ns >= THR) ? runf0 : 0.f;
            const float still = runf0 - stop;
            const float rem = (1.f - hsum0) * stop;
            const float p = hn * still + rem;
            if (kh == 0) p_mine = p;
            ps0 += p;
            steps0 += runf0;   // old running, reference order
            rem0 += rem;
            hsum0 = ns;
            runf0 = still;
            cur0 ^= 1;
            nst0 += 1;
            adv0 = (still == 0.f) || (nst0 == NSTEP);
        }
        if (act1) {
            const float dotv = ((red[8] + red[9]) + (red[10] + red[11])) +
                               ((red[12] + red[13]) + (red[14] + red[15]));
            const float z = dotv + bh;
            const float hn = 1.f / (1.f + expf(-z));
            const float ns = hsum1 + hn;
            const float stop = (ns >= THR) ? runf1 : 0.f;
            const float still = runf1 - stop;
            const float rem = (1.f - hsum1) * stop;
            const float p = hn * still + rem;
            if (kh == 1) p_mine = p;
            ps1 += p;
            steps1 += runf1;
            rem1 += rem;
            hsum1 = ns;
            runf1 = still;
            cur1 ^= 1;
            nst1 += 1;
            adv1 = (still == 0.f) || (nst1 == NSTEP);
        }
        if (myact) sacc_v += p_mine * sn;

        // ---- phase 4: per-row advance (uniform) ----
        const int myadv = kh ? adv1 : adv0;
        if (myadv) {
            const int myt = kh ? t1 : t0;
            sb[kh][kh ? cur1 : cur0][h] = sacc_v;   // s(next t) = s_acc
            sacc_out[((size_t)myt * B_DIM + b0 + kh) * (size_t)H_DIM + h] =
                f2bf(sacc_v);
            if (h == 0) {
                const int bi = myt * B_DIM + b0 + kh;
                psum_g[bi] = kh ? ps1 : ps0;
                rho_out[bi] = (kh ? steps1 + rem1 : steps0 + rem0);
                n_out[bi] = kh ? steps1 : steps0;
            }
            sacc_v = 0.f;
        }
        if (adv0) {
            hsum0 = 0.f; runf0 = 1.f; steps0 = 0.f; rem0 = 0.f; ps0 = 0.f;
            nst0 = 0;
            t0 += 1;
            if (t0 == T_DIM) act0 = 0;
            else if ((t0 & (WIN - 1)) == 0) refill0 = 1;
        }
        if (adv1) {
            hsum1 = 0.f; runf1 = 1.f; steps1 = 0.f; rem1 = 0.f; ps1 = 0.f;
            nst1 = 0;
            t1 += 1;
            if (t1 == T_DIM) act1 = 0;
            else if ((t1 & (WIN - 1)) == 0) refill1 = 1;
        }
        __syncthreads();   // C: sb/sacc writes visible before next stream

        if (refill0 && act0) DO_REFILL(0, t0, b0)
        if (refill1 && act1) DO_REFILL(1, t1, b0 + 1)
        refill0 = 0;
        refill1 = 0;
    }
#undef DO_REFILL
}

// ---------------- y = s_acc @ W_out.T + psum * b_out ----------------
// Reads bf16 s_acc from the y region of d_out, overwrites same rows with y.
__global__ __launch_bounds__(256) void k_y(
    const float* __restrict__ woutT,  // [512][256]
    const float* __restrict__ b_out,
    const float* __restrict__ psum_g,
    float* out)
{
    __shared__ float sl[16][512];
    __shared__ float pl[16];
    const int tid = threadIdx.x;
    const int tb0 = blockIdx.x * 16;
    const unsigned short* sacc = (const unsigned short*)out;
    for (int i = tid; i < 16 * 512; i += 256) {
        unsigned int u = sacc[(size_t)tb0 * 512 + i];
        u <<= 16;
        sl[i >> 9][i & 511] = __uint_as_float(u);
    }
    if (tid < 16) pl[tid] = psum_g[tb0 + tid];
    __syncthreads();
    const int o = tid;
    float acc[16];
#pragma unroll
    for (int r = 0; r < 16; ++r) acc[r] = 0.f;
    for (int hh = 0; hh < 512; hh += 4) {
        const float wv0 = woutT[(hh + 0) * 256 + o];
        const float wv1 = woutT[(hh + 1) * 256 + o];
        const float wv2 = woutT[(hh + 2) * 256 + o];
        const float wv3 = woutT[(hh + 3) * 256 + o];
#pragma unroll
        for (int r = 0; r < 16; ++r) {
            const float4 sv = *(const float4*)&sl[r][hh];
            acc[r] += sv.x * wv0;
            acc[r] += sv.y * wv1;
            acc[r] += sv.z * wv2;
            acc[r] += sv.w * wv3;
        }
    }
    const float bo = b_out[o];
    for (int r = 0; r < 16; ++r)
        out[(size_t)(tb0 + r) * 256 + o] = acc[r] + pl[r] * bo;
}

extern "C" void kernel_launch(void* const* d_in, const int* in_sizes, int n_in,
                              void* d_out, int out_size, void* d_ws, size_t ws_size,
                              hipStream_t stream) {
    const float* x = (const float*)d_in[0];
    const float* W_ih = (const float*)d_in[1];
    const float* b_ih = (const float*)d_in[2];
    const float* W_hh = (const float*)d_in[3];
    const float* b_hh = (const float*)d_in[4];
    const float* W_halt = (const float*)d_in[5];
    const float* b_halt = (const float*)d_in[6];
    const float* W_out = (const float*)d_in[7];
    const float* b_out = (const float*)d_in[8];
    float* out = (float*)d_out;

    char* ws = (char*)d_ws;
    float* whhT = (float*)ws;                                 // 1 MB
    float* wihT = (float*)(ws + (1u << 20));                  // 512 KB
    float* woutT = (float*)(ws + (1u << 20) + (512u << 10));  // 512 KB
    float* psum = (float*)(ws + (2u << 20));                  // 512 KB

    hipLaunchKernelGGL(k_transpose, dim3(2048), dim3(256), 0, stream,
                       W_hh, W_ih, W_out, whhT, wihT, woutT);
    hipLaunchKernelGGL(k_recur7, dim3(B_DIM / 2), dim3(1024), 0, stream,
                       x, wihT, whhT, W_ih, W_halt, b_ih, b_hh, b_halt,
                       out, psum);
    hipLaunchKernelGGL(k_y, dim3((T_DIM * B_DIM) / 16), dim3(256), 0, stream,
                       woutT, b_out, psum, out);
}